// Round 5
// baseline (3917.081 us; speedup 1.0000x reference)
//
#include <hip/hip_runtime.h>
#include <cstdint>
#include <cstddef>

// FPS distance math must be mul/add (never fma-contracted) to match XLA's
// rounding bit-exactly. HIP defaults to -ffp-contract=fast-honor-pragmas,
// so this file-scope pragma is binding. All other kernels use explicit
// __fmaf_rn/__fmul_rn/__fadd_rn intrinsics and are unaffected.
#pragma clang fp contract(off)

#define NPTS    8192
#define NPT     2048      // NPOINT
#define KNB     32        // NSAMPLE
#define NB      4         // batch
#define DPTS    29        // point feature channels
#define CINP    32        // 3 + 29
#define CO      64        // COUT
#define KS      (KNB*NPT)     // 65536 positions per (b, channel)
#define TELEM   ((size_t)NB*CO*KS)  // 16777216 floats per tensor
#define MCNT    262144.0f     // B*K*S for batch-norm
#define BNEPS   1e-5f
#define FTHR    256       // FPS threads (R10: 1 wave/SIMD)
#define FWAVES  (FTHR/64) // 4 waves
#define FPT     32        // points per thread (256*32 = 8192)

// ---------------------------------------------------------------- FPS
// One block per batch, 256 threads (1 wave/SIMD). Cost-model evidence:
// busy/SIMD/iter fits n_waves*F + C with F ~= 443 (per-wave fixed overhead:
// DPP reduce, ballot, skey exchange, block tree, addressing) and C ~= 547
// (distance-work share). Measured: 2 waves -> 1434 (R4), 4 waves -> 2321
// (R3). 1 wave/SIMD predicts ~990 busy. Serial depth is exposed at 1
// wave/SIMD, so the per-thread argmax is a depth-5 (value,index) tournament
// tree instead of a 32-step cndmask chain.
// Numerics: strict IEEE sub/mul/add ((dx^2+dy^2)+dz^2), contraction off.
// Tournament with '>=' picks the lower index on ties at every node =>
// root j = lowest index achieving the max (= jnp.argmax first-occurrence),
// and root v is bitwise tb (max is associative, all values non-NaN >= +0).
// Lowest-lane ballot pick = lowest gidx (base monotonic in lane); u64
// (dist||~gidx) cross-wave keys => global first-occurrence exact.
typedef float v2f __attribute__((ext_vector_type(2)));

static __device__ __forceinline__ unsigned long long umax64(unsigned long long a,
                                                            unsigned long long b) {
    return a > b ? a : b;
}

__global__ __launch_bounds__(FTHR) void fps_kernel(const float* __restrict__ xyz,
                                                   float* __restrict__ out0) {
    const int b = blockIdx.x;
    const int t = threadIdx.x;          // 0..255
    const int lane = t & 63;
    const int wid  = t >> 6;            // 0..3
    const float* xb = xyz + (size_t)b * 3 * NPTS;
    const int base = t * FPT;

    // dynamic LDS: cloud copy (96 KB) + winner coords (24 KB) + skey[2][4]
    extern __shared__ float smem[];
    float* sx = smem;
    float* sy = sx + NPTS;
    float* sz = sy + NPTS;
    float* sc = sz + NPTS;                                   // [3][NPT]
    unsigned long long* skey = (unsigned long long*)(sc + 3 * NPT); // [2][4]

    // coords as 16 register pairs per axis (points 2p, 2p+1), distances d[32].
    // All indices compile-time constant (full unroll) -> registers.
    v2f px[16], py[16], pz[16];
    float d[32];
    {
        const float4* x4 = (const float4*)(xb + base);
        const float4* y4 = (const float4*)(xb + NPTS + base);
        const float4* z4 = (const float4*)(xb + 2 * NPTS + base);
        float4* lx4 = (float4*)(sx + base);
        float4* ly4 = (float4*)(sy + base);
        float4* lz4 = (float4*)(sz + base);
#pragma unroll
        for (int u = 0; u < 8; ++u) {
            float4 v;
            v = x4[u]; lx4[u] = v; px[2*u] = (v2f){v.x, v.y}; px[2*u+1] = (v2f){v.z, v.w};
            v = y4[u]; ly4[u] = v; py[2*u] = (v2f){v.x, v.y}; py[2*u+1] = (v2f){v.z, v.w};
            v = z4[u]; lz4[u] = v; pz[2*u] = (v2f){v.x, v.y}; pz[2*u+1] = (v2f){v.z, v.w};
        }
#pragma unroll
        for (int k = 0; k < 32; ++k) d[k] = 1e10f;
    }

    // initial centroid = point 0 (broadcast global load; LDS copy not yet synced)
    float cx = xb[0], cy = xb[NPTS], cz = xb[2 * NPTS];
    float* ob = out0 + (size_t)b * 3 * NPT;
    if (t == 0) { sc[0] = cx; sc[NPT] = cy; sc[2 * NPT] = cz; }

    for (int i = 1; i < NPT; ++i) {
        // negated centroid broadcast pairs (p + (-c) == p - c, exact)
        const v2f ncx = (v2f){-cx, -cx};
        const v2f ncy = (v2f){-cy, -cy};
        const v2f ncz = (v2f){-cz, -cz};
#pragma unroll
        for (int p = 0; p < 16; ++p) {
            v2f dx = px[p] + ncx;
            v2f dy = py[p] + ncy;
            v2f dz = pz[p] + ncz;
            v2f dd = (dx * dx + dy * dy) + dz * dz;
            d[2*p]   = fminf(d[2*p],   dd.x);
            d[2*p+1] = fminf(d[2*p+1], dd.y);
        }

        // (value, index) tournament tree, depth 5. '>= keeps lower index'
        // on ties at every node => first-occurrence argmax, bit-exact.
        float v16[16]; int j16[16];
#pragma unroll
        for (int k = 0; k < 16; ++k) {
            v16[k] = fmaxf(d[2*k], d[2*k+1]);
            j16[k] = (d[2*k] >= d[2*k+1]) ? 2*k : 2*k+1;
        }
        float v8[8]; int j8[8];
#pragma unroll
        for (int k = 0; k < 8; ++k) {
            v8[k] = fmaxf(v16[2*k], v16[2*k+1]);
            j8[k] = (v16[2*k] >= v16[2*k+1]) ? j16[2*k] : j16[2*k+1];
        }
        float v4[4]; int j4[4];
#pragma unroll
        for (int k = 0; k < 4; ++k) {
            v4[k] = fmaxf(v8[2*k], v8[2*k+1]);
            j4[k] = (v8[2*k] >= v8[2*k+1]) ? j8[2*k] : j8[2*k+1];
        }
        float v2[2]; int j2[2];
#pragma unroll
        for (int k = 0; k < 2; ++k) {
            v2[k] = fmaxf(v4[2*k], v4[2*k+1]);
            j2[k] = (v4[2*k] >= v4[2*k+1]) ? j4[2*k] : j4[2*k+1];
        }
        const float tb = fmaxf(v2[0], v2[1]);
        const int   jj = (v2[0] >= v2[1]) ? j2[0] : j2[1];
        const int gidx = base + jj;

        // wave max via DPP: result accumulates into lane 63.
        // s_nop 1 = 2 wait states for the VALU->DPP RAW hazard.
        float r = tb;
        asm volatile(
            "s_nop 1\n\t"
            "v_max_f32 %0, %0, %0 row_shr:1\n\t"
            "s_nop 1\n\t"
            "v_max_f32 %0, %0, %0 row_shr:2\n\t"
            "s_nop 1\n\t"
            "v_max_f32 %0, %0, %0 row_shr:4\n\t"
            "s_nop 1\n\t"
            "v_max_f32 %0, %0, %0 row_shr:8\n\t"
            "s_nop 1\n\t"
            "v_max_f32 %0, %0, %0 row_bcast:15 row_mask:0xa\n\t"
            "s_nop 1\n\t"
            "v_max_f32 %0, %0, %0 row_bcast:31 row_mask:0xc\n\t"
            "s_nop 1"
            : "+v"(r));
        const float wm = __uint_as_float(
            (unsigned int)__builtin_amdgcn_readlane((int)__float_as_uint(r), 63));

        // winner lane = lowest lane holding wm (= lowest gidx within wave)
        unsigned long long eq = __ballot(tb == wm);
        const int lwin = __ffsll((long long)eq) - 1;
        const int wgid = __builtin_amdgcn_readlane(gidx, lwin);

        const int par = i & 1;
        if (lane == 0)
            skey[par * FWAVES + wid] =
                (((unsigned long long)__float_as_uint(wm)) << 32) |
                (unsigned int)(~(unsigned int)wgid);
        __syncthreads();

        // block reduce: read all 4 wave keys, register max-tree
        const ulonglong2* sk2 = (const ulonglong2*)(skey + par * FWAVES);
        ulonglong2 k01 = sk2[0], k23 = sk2[1];
        unsigned long long kbest = umax64(umax64(k01.x, k01.y),
                                          umax64(k23.x, k23.y));
        const int widx = (int)(~(unsigned int)kbest);

        // broadcast coord fetch from LDS cloud copy; stage winner in LDS
        // (zero vmem in loop: no vmcnt drain at the barrier)
        cx = sx[widx]; cy = sy[widx]; cz = sz[widx];
        if (t == 0) { sc[i] = cx; sc[NPT + i] = cy; sc[2 * NPT + i] = cz; }
        // no 2nd barrier: skey parity double-buffered (hazard proof: every
        // wave's read of skey[par] precedes its own next-iteration barrier,
        // and writes to skey[par] recur only after that barrier)
    }

    // bulk copy winner coords LDS -> global, coalesced float4
    __syncthreads();
    const float4* s4 = (const float4*)sc;
    float4* o4 = (float4*)ob;
#pragma unroll
    for (int e = t; e < 3 * NPT / 4; e += FTHR) o4[e] = s4[e];
}

// ---------------------------------------------------------------- ball query
// One wave per (b, s). 32 smallest in-radius indices (ascending scan +
// ballot compaction), padded with the first hit. LDS buffer is wave-private
// -> no block barrier needed (compiler's lgkmcnt tracking orders the RAW).
__global__ __launch_bounds__(256) void ballq_kernel(const float* __restrict__ xyz,
                                                    const float* __restrict__ out0,
                                                    int* __restrict__ idx) {
    const int gw   = (blockIdx.x * 256 + threadIdx.x) >> 6;  // 0..8191
    const int lane = threadIdx.x & 63;
    const int b  = gw >> 11;
    const int si = gw & 2047;
    const float* xb = xyz + (size_t)b * 3 * NPTS;

    const float cx = out0[b * 3 * NPT + si];
    const float cy = out0[b * 3 * NPT + NPT + si];
    const float cz = out0[b * 3 * NPT + 2*NPT + si];
    const float csum = __fadd_rn(__fadd_rn(__fmul_rn(cx, cx), __fmul_rn(cy, cy)),
                                 __fmul_rn(cz, cz));
    const float R2 = (float)(0.1 * 0.1);  // 0x3C23D70A — NOT 0.1f*0.1f!

    __shared__ int buf[4][KNB];
    int* mybuf = buf[threadIdx.x >> 6];

    int cnt = 0;
    for (int n0 = 0; n0 < NPTS && cnt < KNB; n0 += 64) {
        const int i = n0 + lane;
        float pxv = xb[i], pyv = xb[NPTS + i], pzv = xb[2 * NPTS + i];
        float ps = __fadd_rn(__fadd_rn(__fmul_rn(pxv, pxv), __fmul_rn(pyv, pyv)),
                             __fmul_rn(pzv, pzv));
        float dot = __fmaf_rn(pzv, cz, __fmaf_rn(pyv, cy, __fmul_rn(pxv, cx)));
        float sqr = __fsub_rn(__fadd_rn(csum, ps), __fadd_rn(dot, dot));
        bool hit = (sqr <= R2);
        unsigned long long m = __ballot(hit);
        int pos = cnt + __popcll(m & ((1ull << lane) - 1ull));
        if (hit && pos < KNB) mybuf[pos] = i;
        cnt += __popcll(m);
    }
    int c = cnt < KNB ? cnt : KNB;
    int first = (cnt > 0) ? mybuf[0] : 0;
    if (lane < KNB) {
        int v = (lane < c) ? mybuf[lane] : first;
        idx[((size_t)gw << 5) + lane] = v;
    }
}

// ---------------------------------------------------------------- proj conv
// Fused gather/concat + conv(32->64) + BN-stats accumulation.
__global__ __launch_bounds__(256) void proj_kernel(const float* __restrict__ xyz,
                                                   const float* __restrict__ points,
                                                   const float* __restrict__ out0,
                                                   const int* __restrict__ idx,
                                                   const float* __restrict__ W,
                                                   float* __restrict__ out,
                                                   float* __restrict__ stats) {
    const int p = blockIdx.x * 256 + threadIdx.x;   // 0..262143
    const int b = p >> 16;
    const int q = p & 65535;       // k*NPT + s
    const int k = q >> 11;
    const int s = q & 2047;
    const int tid = threadIdx.x;

    __shared__ float ssum[CO], ssq[CO];
    if (tid < CO) { ssum[tid] = 0.f; ssq[tid] = 0.f; }
    __syncthreads();

    const int j = idx[((size_t)(b * NPT + s) << 5) + k];
    const float* xb = xyz + (size_t)b * 3 * NPTS;
    float a[CINP];
    a[0] = xb[j]            - out0[b * 3 * NPT + s];
    a[1] = xb[NPTS + j]     - out0[b * 3 * NPT + NPT + s];
    a[2] = xb[2*NPTS + j]   - out0[b * 3 * NPT + 2*NPT + s];
    const float* pb = points + (size_t)b * DPTS * NPTS;
#pragma unroll
    for (int c = 0; c < DPTS; ++c) a[3 + c] = pb[c * NPTS + j];

    const size_t obase = (size_t)b * CO * KS + q;
    for (int o = 0; o < CO; ++o) {
        float acc = 0.f;
#pragma unroll
        for (int c = 0; c < CINP; ++c) acc = __fmaf_rn(W[o * CINP + c], a[c], acc);
        out[obase + (size_t)o * KS] = acc;
        float s1 = acc, s2 = acc * acc;
#pragma unroll
        for (int off = 32; off > 0; off >>= 1) {
            s1 += __shfl_xor(s1, off, 64);
            s2 += __shfl_xor(s2, off, 64);
        }
        if ((tid & 63) == 0) { atomicAdd(&ssum[o], s1); atomicAdd(&ssq[o], s2); }
    }
    __syncthreads();
    if (tid < CO) {
        atomicAdd(&stats[tid], ssum[tid]);
        atomicAdd(&stats[CO + tid], ssq[tid]);
    }
}

// ---------------------------------------------------------------- fused conv
// input-BN (+optional residual) + relu -> GEMM 64x64 -> raw out + stats.
// NOTE: in/idn/act_out/out may ALIAS (in-place use): no __restrict__ on them.
// Safe because each thread touches only its own q-column {base + i*KS}, and
// all its loads (loop 1) precede all its stores of loop 2 in program order.
template <bool HAS_IDN, bool WRITE_ACT>
__global__ __launch_bounds__(256) void conv_bn_kernel(const float* in,
                                                      const float* idn,
                                                      const float* __restrict__ stats_in,
                                                      const float* __restrict__ gamma,
                                                      const float* __restrict__ beta,
                                                      const float* __restrict__ W,
                                                      float* act_out,
                                                      float* out,
                                                      float* __restrict__ stats_out) {
    const int p = blockIdx.x * 256 + threadIdx.x;
    const int b = p >> 16;
    const int q = p & 65535;
    const int tid = threadIdx.x;

    __shared__ float ssc[CO], ssh[CO], ssum[CO], ssq[CO];
    if (tid < CO) {
        const float Minv = 1.0f / MCNT;
        float m = stats_in[tid] * Minv;
        float v = stats_in[CO + tid] * Minv - m * m;
        float scl = gamma[tid] * rsqrtf(v + BNEPS);
        ssc[tid] = scl;
        ssh[tid] = beta[tid] - m * scl;
        ssum[tid] = 0.f; ssq[tid] = 0.f;
    }
    __syncthreads();

    const size_t base = (size_t)b * CO * KS + q;
    float a[CO];
#pragma unroll
    for (int c = 0; c < CO; ++c) {
        float v = __fmaf_rn(ssc[c], in[base + (size_t)c * KS], ssh[c]);
        if (HAS_IDN) v += idn[base + (size_t)c * KS];
        v = fmaxf(v, 0.0f);
        a[c] = v;
        if (WRITE_ACT) act_out[base + (size_t)c * KS] = v;
    }
    for (int o = 0; o < CO; ++o) {
        float acc = 0.f;
#pragma unroll
        for (int c = 0; c < CO; ++c) acc = __fmaf_rn(W[o * CO + c], a[c], acc);
        out[base + (size_t)o * KS] = acc;
        float s1 = acc, s2 = acc * acc;
#pragma unroll
        for (int off = 32; off > 0; off >>= 1) {
            s1 += __shfl_xor(s1, off, 64);
            s2 += __shfl_xor(s2, off, 64);
        }
        if ((tid & 63) == 0) { atomicAdd(&ssum[o], s1); atomicAdd(&ssq[o], s2); }
    }
    __syncthreads();
    if (tid < CO) {
        atomicAdd(&stats_out[tid], ssum[tid]);
        atomicAdd(&stats_out[CO + tid], ssq[tid]);
    }
}

// ---------------------------------------------------------------- final
// BN + residual + relu + maxpool over k.
__global__ __launch_bounds__(256) void final_kernel(const float* __restrict__ y2,
                                                    const float* __restrict__ idn,
                                                    const float* __restrict__ stats,
                                                    const float* __restrict__ gamma,
                                                    const float* __restrict__ beta,
                                                    float* __restrict__ feat) {
    const int p = blockIdx.x * 256 + threadIdx.x;   // 0..524287
    const int s = p & 2047;
    const int o = (p >> 11) & 63;
    const int b = p >> 17;
    const float Minv = 1.0f / MCNT;
    float m = stats[o] * Minv;
    float v = stats[CO + o] * Minv - m * m;
    float scl = gamma[o] * rsqrtf(v + BNEPS);
    float sh  = beta[o] - m * scl;
    const size_t base = (size_t)b * CO * KS + (size_t)o * KS + s;
    float mx = -1e30f;
#pragma unroll
    for (int k = 0; k < KNB; ++k) {
        float val = __fmaf_rn(scl, y2[base + (size_t)k * NPT], sh) + idn[base + (size_t)k * NPT];
        val = fmaxf(val, 0.0f);
        mx = fmaxf(mx, val);
    }
    feat[p] = mx;
}

__global__ void zero_kernel(float* p, int n) {
    int i = blockIdx.x * blockDim.x + threadIdx.x;
    if (i < n) p[i] = 0.f;
}

extern "C" void kernel_launch(void* const* d_in, const int* in_sizes, int n_in,
                              void* d_out, int out_size, void* d_ws, size_t ws_size,
                              hipStream_t stream) {
    (void)in_sizes; (void)n_in; (void)out_size; (void)ws_size;
    const float* xyz    = (const float*)d_in[0];
    const float* points = (const float*)d_in[1];
    const float* proj_w = (const float*)d_in[2];
    const float* proj_g = (const float*)d_in[3];
    const float* proj_b = (const float*)d_in[4];
    const float* w1     = (const float*)d_in[5];   // (2,64,64)
    const float* g1     = (const float*)d_in[6];
    const float* b1     = (const float*)d_in[7];
    const float* w2     = (const float*)d_in[8];
    const float* g2     = (const float*)d_in[9];
    const float* b2     = (const float*)d_in[10];

    float* out0 = (float*)d_out;                   // (4,3,2048)
    float* feat = (float*)d_out + NB * 3 * NPT;    // (4,64,2048)

    // Workspace layout: small arrays first, then TWO big tensors (A, B).
    // Total: (1024 + 262144 + 2*16777216) * 4 B = 135.3 MB.
    float* stats = (float*)d_ws;                    // 5 x 128 (rounded to 1024)
    int*   idx   = (int*)((float*)d_ws + 1024);     // (4,2048,32)
    float* A     = (float*)(idx + NB * NPT * KNB);  // activation tensor
    float* B     = A + TELEM;                       // residual tensor

    // cloud copy (96 KB) + winner-coord staging (24 KB) + skey (64 B)
    const size_t fps_lds = (size_t)(3 * NPTS + 3 * NPT) * sizeof(float)
                         + 2 * FWAVES * sizeof(unsigned long long);  // 122,944 B

    hipLaunchKernelGGL(zero_kernel, dim3(3), dim3(256), 0, stream, stats, 5 * 2 * CO);
    hipLaunchKernelGGL(fps_kernel, dim3(NB), dim3(FTHR), fps_lds, stream, xyz, out0);
    hipLaunchKernelGGL(ballq_kernel, dim3(2048), dim3(256), 0, stream, xyz, out0, idx);
    // proj raw conv -> A, stats0
    hipLaunchKernelGGL(proj_kernel, dim3(1024), dim3(256), 0, stream,
                       xyz, points, out0, idx, proj_w, A, stats);
    // d=0: x = relu(bnP(A)); idn0 -> B; y1 -> A (in-place)
    hipLaunchKernelGGL((conv_bn_kernel<false, true>), dim3(1024), dim3(256), 0, stream,
                       A, (const float*)nullptr, stats, proj_g, proj_b, w1,
                       B, A, stats + 128);
    // d=0: y2 = conv(w2[0], relu(bn1(y1)))  A -> A
    hipLaunchKernelGGL((conv_bn_kernel<false, false>), dim3(1024), dim3(256), 0, stream,
                       A, (const float*)nullptr, stats + 128, g1, b1, w2,
                       (float*)nullptr, A, stats + 256);
    // d=1: x = relu(bn2(y2)+idn0); idn1 -> B (aliases idn read); y1 -> A
    hipLaunchKernelGGL((conv_bn_kernel<true, true>), dim3(1024), dim3(256), 0, stream,
                       A, B, stats + 256, g2, b2, w1 + CO * CO,
                       B, A, stats + 384);
    // d=1: y2 = conv(w2[1], relu(bn1'(y1)))  A -> A
    hipLaunchKernelGGL((conv_bn_kernel<false, false>), dim3(1024), dim3(256), 0, stream,
                       A, (const float*)nullptr, stats + 384, g1 + CO, b1 + CO, w2 + CO * CO,
                       (float*)nullptr, A, stats + 512);
    // feat = max_k relu(bn2'(A)+B)
    hipLaunchKernelGGL(final_kernel, dim3(2048), dim3(256), 0, stream,
                       A, B, stats + 512, g2 + CO, b2 + CO, feat);
}

// Round 6
// 2346.572 us; speedup vs baseline: 1.6693x; 1.6693x over previous
//
#include <hip/hip_runtime.h>
#include <cstdint>
#include <cstddef>

// FPS distance math must be mul/add (never fma-contracted) to match XLA's
// rounding bit-exactly. HIP defaults to -ffp-contract=fast-honor-pragmas,
// so this file-scope pragma is binding. All other kernels use explicit
// __fmaf_rn/__fmul_rn/__fadd_rn intrinsics and are unaffected.
#pragma clang fp contract(off)

#define NPTS    8192
#define NPT     2048      // NPOINT
#define KNB     32        // NSAMPLE
#define NB      4         // batch
#define DPTS    29        // point feature channels
#define CINP    32        // 3 + 29
#define CO      64        // COUT
#define KS      (KNB*NPT)     // 65536 positions per (b, channel)
#define TELEM   ((size_t)NB*CO*KS)  // 16777216 floats per tensor
#define MCNT    262144.0f     // B*K*S for batch-norm
#define BNEPS   1e-5f
#define FTHR    256       // FPS threads (1 wave/SIMD)
#define FWAVES  (FTHR/64) // 4 waves
#define FPT     32        // points per thread (256*32 = 8192)

// ---------------------------------------------------------------- FPS
// One block per batch, 256 threads (1 wave/SIMD). R11 = R10 retried with
// the two execution faults fixed:
//  * R10's VGPR_Count=84 vs ~150 needed -> compiler spilled coord arrays
//    to scratch (FETCH 206->221 KB, 34 ms outlier dispatches). Fix:
//    __launch_bounds__(FTHR, 1) -> min 1 wave/EU -> full register budget.
//  * Tournament tree doubled live values exactly when the budget shrank.
//    Reverted to the proven descending cndmask scan (inline consts,
//    cheapest measured form across R1/R2/R4) + in-loop tb accumulation.
// Cost model under test (fit from R3/R4): busy/SIMD/iter = waves*F + C,
// F ~= 443 (per-wave overhead), C ~= 547 (distance work). 1 wave/SIMD
// predicts ~990 busy vs 1434 at 2 waves. Falsifier: fps >= 1750 us.
// Numerics: strict IEEE sub/mul/add ((dx^2+dy^2)+dz^2), contraction off;
// descending == scan keeps lowest j achieving tb (tb bitwise member of d);
// lowest-lane ballot; u64 (dist||~gidx) keys => first-occurrence exact.
typedef float v2f __attribute__((ext_vector_type(2)));

static __device__ __forceinline__ unsigned long long umax64(unsigned long long a,
                                                            unsigned long long b) {
    return a > b ? a : b;
}

__global__ __launch_bounds__(FTHR, 1) void fps_kernel(const float* __restrict__ xyz,
                                                      float* __restrict__ out0) {
    const int b = blockIdx.x;
    const int t = threadIdx.x;          // 0..255
    const int lane = t & 63;
    const int wid  = t >> 6;            // 0..3
    const float* xb = xyz + (size_t)b * 3 * NPTS;
    const int base = t * FPT;

    // dynamic LDS: cloud copy (96 KB) + winner coords (24 KB) + skey[2][4]
    extern __shared__ float smem[];
    float* sx = smem;
    float* sy = sx + NPTS;
    float* sz = sy + NPTS;
    float* sc = sz + NPTS;                                   // [3][NPT]
    unsigned long long* skey = (unsigned long long*)(sc + 3 * NPT); // [2][4]

    // coords as 16 register pairs per axis (points 2p, 2p+1), distances d[32].
    // All indices compile-time constant (full unroll) -> registers.
    v2f px[16], py[16], pz[16];
    float d[32];
    {
        const float4* x4 = (const float4*)(xb + base);
        const float4* y4 = (const float4*)(xb + NPTS + base);
        const float4* z4 = (const float4*)(xb + 2 * NPTS + base);
        float4* lx4 = (float4*)(sx + base);
        float4* ly4 = (float4*)(sy + base);
        float4* lz4 = (float4*)(sz + base);
#pragma unroll
        for (int u = 0; u < 8; ++u) {
            float4 v;
            v = x4[u]; lx4[u] = v; px[2*u] = (v2f){v.x, v.y}; px[2*u+1] = (v2f){v.z, v.w};
            v = y4[u]; ly4[u] = v; py[2*u] = (v2f){v.x, v.y}; py[2*u+1] = (v2f){v.z, v.w};
            v = z4[u]; lz4[u] = v; pz[2*u] = (v2f){v.x, v.y}; pz[2*u+1] = (v2f){v.z, v.w};
        }
#pragma unroll
        for (int k = 0; k < 32; ++k) d[k] = 1e10f;
    }

    // initial centroid = point 0 (broadcast global load; LDS copy not yet synced)
    float cx = xb[0], cy = xb[NPTS], cz = xb[2 * NPTS];
    float* ob = out0 + (size_t)b * 3 * NPT;
    if (t == 0) { sc[0] = cx; sc[NPT] = cy; sc[2 * NPT] = cz; }

    for (int i = 1; i < NPT; ++i) {
        // negated centroid broadcast pairs (p + (-c) == p - c, exact)
        const v2f ncx = (v2f){-cx, -cx};
        const v2f ncy = (v2f){-cy, -cy};
        const v2f ncz = (v2f){-cz, -cz};
        float tb = -1.0f;
#pragma unroll
        for (int p = 0; p < 16; ++p) {
            v2f dx = px[p] + ncx;
            v2f dy = py[p] + ncy;
            v2f dz = pz[p] + ncz;
            v2f dd = (dx * dx + dy * dy) + dz * dz;
            float ndA = fminf(d[2*p],   dd.x);  d[2*p]   = ndA;
            float ndB = fminf(d[2*p+1], dd.y);  d[2*p+1] = ndB;
            tb = fmaxf(tb, fmaxf(ndA, ndB));
        }

        // first-match (lowest j): descending cndmask scan, inline consts,
        // last write wins (proven cheapest form R1/R2/R4)
        int jj = 0;
#pragma unroll
        for (int k = 31; k >= 0; --k) jj = (d[k] == tb) ? k : jj;
        const int gidx = base + jj;

        // wave max via DPP: result accumulates into lane 63.
        // s_nop 1 = 2 wait states for the VALU->DPP RAW hazard.
        float r = tb;
        asm volatile(
            "s_nop 1\n\t"
            "v_max_f32 %0, %0, %0 row_shr:1\n\t"
            "s_nop 1\n\t"
            "v_max_f32 %0, %0, %0 row_shr:2\n\t"
            "s_nop 1\n\t"
            "v_max_f32 %0, %0, %0 row_shr:4\n\t"
            "s_nop 1\n\t"
            "v_max_f32 %0, %0, %0 row_shr:8\n\t"
            "s_nop 1\n\t"
            "v_max_f32 %0, %0, %0 row_bcast:15 row_mask:0xa\n\t"
            "s_nop 1\n\t"
            "v_max_f32 %0, %0, %0 row_bcast:31 row_mask:0xc\n\t"
            "s_nop 1"
            : "+v"(r));
        const float wm = __uint_as_float(
            (unsigned int)__builtin_amdgcn_readlane((int)__float_as_uint(r), 63));

        // winner lane = lowest lane holding wm (= lowest gidx within wave)
        unsigned long long eq = __ballot(tb == wm);
        const int lwin = __ffsll((long long)eq) - 1;
        const int wgid = __builtin_amdgcn_readlane(gidx, lwin);

        const int par = i & 1;
        if (lane == 0)
            skey[par * FWAVES + wid] =
                (((unsigned long long)__float_as_uint(wm)) << 32) |
                (unsigned int)(~(unsigned int)wgid);
        __syncthreads();

        // block reduce: read all 4 wave keys, register max-tree
        const ulonglong2* sk2 = (const ulonglong2*)(skey + par * FWAVES);
        ulonglong2 k01 = sk2[0], k23 = sk2[1];
        unsigned long long kbest = umax64(umax64(k01.x, k01.y),
                                          umax64(k23.x, k23.y));
        const int widx = (int)(~(unsigned int)kbest);

        // broadcast coord fetch from LDS cloud copy; stage winner in LDS
        // (zero vmem in loop: no vmcnt drain at the barrier)
        cx = sx[widx]; cy = sy[widx]; cz = sz[widx];
        if (t == 0) { sc[i] = cx; sc[NPT + i] = cy; sc[2 * NPT + i] = cz; }
        // no 2nd barrier: skey parity double-buffered (hazard proof: every
        // wave's read of skey[par] precedes its own next-iteration barrier,
        // and writes to skey[par] recur only after that barrier)
    }

    // bulk copy winner coords LDS -> global, coalesced float4
    __syncthreads();
    const float4* s4 = (const float4*)sc;
    float4* o4 = (float4*)ob;
#pragma unroll
    for (int e = t; e < 3 * NPT / 4; e += FTHR) o4[e] = s4[e];
}

// ---------------------------------------------------------------- ball query
// One wave per (b, s). 32 smallest in-radius indices (ascending scan +
// ballot compaction), padded with the first hit. LDS buffer is wave-private
// -> no block barrier needed (compiler's lgkmcnt tracking orders the RAW).
__global__ __launch_bounds__(256) void ballq_kernel(const float* __restrict__ xyz,
                                                    const float* __restrict__ out0,
                                                    int* __restrict__ idx) {
    const int gw   = (blockIdx.x * 256 + threadIdx.x) >> 6;  // 0..8191
    const int lane = threadIdx.x & 63;
    const int b  = gw >> 11;
    const int si = gw & 2047;
    const float* xb = xyz + (size_t)b * 3 * NPTS;

    const float cx = out0[b * 3 * NPT + si];
    const float cy = out0[b * 3 * NPT + NPT + si];
    const float cz = out0[b * 3 * NPT + 2*NPT + si];
    const float csum = __fadd_rn(__fadd_rn(__fmul_rn(cx, cx), __fmul_rn(cy, cy)),
                                 __fmul_rn(cz, cz));
    const float R2 = (float)(0.1 * 0.1);  // 0x3C23D70A — NOT 0.1f*0.1f!

    __shared__ int buf[4][KNB];
    int* mybuf = buf[threadIdx.x >> 6];

    int cnt = 0;
    for (int n0 = 0; n0 < NPTS && cnt < KNB; n0 += 64) {
        const int i = n0 + lane;
        float pxv = xb[i], pyv = xb[NPTS + i], pzv = xb[2 * NPTS + i];
        float ps = __fadd_rn(__fadd_rn(__fmul_rn(pxv, pxv), __fmul_rn(pyv, pyv)),
                             __fmul_rn(pzv, pzv));
        float dot = __fmaf_rn(pzv, cz, __fmaf_rn(pyv, cy, __fmul_rn(pxv, cx)));
        float sqr = __fsub_rn(__fadd_rn(csum, ps), __fadd_rn(dot, dot));
        bool hit = (sqr <= R2);
        unsigned long long m = __ballot(hit);
        int pos = cnt + __popcll(m & ((1ull << lane) - 1ull));
        if (hit && pos < KNB) mybuf[pos] = i;
        cnt += __popcll(m);
    }
    int c = cnt < KNB ? cnt : KNB;
    int first = (cnt > 0) ? mybuf[0] : 0;
    if (lane < KNB) {
        int v = (lane < c) ? mybuf[lane] : first;
        idx[((size_t)gw << 5) + lane] = v;
    }
}

// ---------------------------------------------------------------- proj conv
// Fused gather/concat + conv(32->64) + BN-stats accumulation.
__global__ __launch_bounds__(256) void proj_kernel(const float* __restrict__ xyz,
                                                   const float* __restrict__ points,
                                                   const float* __restrict__ out0,
                                                   const int* __restrict__ idx,
                                                   const float* __restrict__ W,
                                                   float* __restrict__ out,
                                                   float* __restrict__ stats) {
    const int p = blockIdx.x * 256 + threadIdx.x;   // 0..262143
    const int b = p >> 16;
    const int q = p & 65535;       // k*NPT + s
    const int k = q >> 11;
    const int s = q & 2047;
    const int tid = threadIdx.x;

    __shared__ float ssum[CO], ssq[CO];
    if (tid < CO) { ssum[tid] = 0.f; ssq[tid] = 0.f; }
    __syncthreads();

    const int j = idx[((size_t)(b * NPT + s) << 5) + k];
    const float* xb = xyz + (size_t)b * 3 * NPTS;
    float a[CINP];
    a[0] = xb[j]            - out0[b * 3 * NPT + s];
    a[1] = xb[NPTS + j]     - out0[b * 3 * NPT + NPT + s];
    a[2] = xb[2*NPTS + j]   - out0[b * 3 * NPT + 2*NPT + s];
    const float* pb = points + (size_t)b * DPTS * NPTS;
#pragma unroll
    for (int c = 0; c < DPTS; ++c) a[3 + c] = pb[c * NPTS + j];

    const size_t obase = (size_t)b * CO * KS + q;
    for (int o = 0; o < CO; ++o) {
        float acc = 0.f;
#pragma unroll
        for (int c = 0; c < CINP; ++c) acc = __fmaf_rn(W[o * CINP + c], a[c], acc);
        out[obase + (size_t)o * KS] = acc;
        float s1 = acc, s2 = acc * acc;
#pragma unroll
        for (int off = 32; off > 0; off >>= 1) {
            s1 += __shfl_xor(s1, off, 64);
            s2 += __shfl_xor(s2, off, 64);
        }
        if ((tid & 63) == 0) { atomicAdd(&ssum[o], s1); atomicAdd(&ssq[o], s2); }
    }
    __syncthreads();
    if (tid < CO) {
        atomicAdd(&stats[tid], ssum[tid]);
        atomicAdd(&stats[CO + tid], ssq[tid]);
    }
}

// ---------------------------------------------------------------- fused conv
// input-BN (+optional residual) + relu -> GEMM 64x64 -> raw out + stats.
// NOTE: in/idn/act_out/out may ALIAS (in-place use): no __restrict__ on them.
// Safe because each thread touches only its own q-column {base + i*KS}, and
// all its loads (loop 1) precede all its stores of loop 2 in program order.
template <bool HAS_IDN, bool WRITE_ACT>
__global__ __launch_bounds__(256) void conv_bn_kernel(const float* in,
                                                      const float* idn,
                                                      const float* __restrict__ stats_in,
                                                      const float* __restrict__ gamma,
                                                      const float* __restrict__ beta,
                                                      const float* __restrict__ W,
                                                      float* act_out,
                                                      float* out,
                                                      float* __restrict__ stats_out) {
    const int p = blockIdx.x * 256 + threadIdx.x;
    const int b = p >> 16;
    const int q = p & 65535;
    const int tid = threadIdx.x;

    __shared__ float ssc[CO], ssh[CO], ssum[CO], ssq[CO];
    if (tid < CO) {
        const float Minv = 1.0f / MCNT;
        float m = stats_in[tid] * Minv;
        float v = stats_in[CO + tid] * Minv - m * m;
        float scl = gamma[tid] * rsqrtf(v + BNEPS);
        ssc[tid] = scl;
        ssh[tid] = beta[tid] - m * scl;
        ssum[tid] = 0.f; ssq[tid] = 0.f;
    }
    __syncthreads();

    const size_t base = (size_t)b * CO * KS + q;
    float a[CO];
#pragma unroll
    for (int c = 0; c < CO; ++c) {
        float v = __fmaf_rn(ssc[c], in[base + (size_t)c * KS], ssh[c]);
        if (HAS_IDN) v += idn[base + (size_t)c * KS];
        v = fmaxf(v, 0.0f);
        a[c] = v;
        if (WRITE_ACT) act_out[base + (size_t)c * KS] = v;
    }
    for (int o = 0; o < CO; ++o) {
        float acc = 0.f;
#pragma unroll
        for (int c = 0; c < CO; ++c) acc = __fmaf_rn(W[o * CO + c], a[c], acc);
        out[base + (size_t)o * KS] = acc;
        float s1 = acc, s2 = acc * acc;
#pragma unroll
        for (int off = 32; off > 0; off >>= 1) {
            s1 += __shfl_xor(s1, off, 64);
            s2 += __shfl_xor(s2, off, 64);
        }
        if ((tid & 63) == 0) { atomicAdd(&ssum[o], s1); atomicAdd(&ssq[o], s2); }
    }
    __syncthreads();
    if (tid < CO) {
        atomicAdd(&stats_out[tid], ssum[tid]);
        atomicAdd(&stats_out[CO + tid], ssq[tid]);
    }
}

// ---------------------------------------------------------------- final
// BN + residual + relu + maxpool over k.
__global__ __launch_bounds__(256) void final_kernel(const float* __restrict__ y2,
                                                    const float* __restrict__ idn,
                                                    const float* __restrict__ stats,
                                                    const float* __restrict__ gamma,
                                                    const float* __restrict__ beta,
                                                    float* __restrict__ feat) {
    const int p = blockIdx.x * 256 + threadIdx.x;   // 0..524287
    const int s = p & 2047;
    const int o = (p >> 11) & 63;
    const int b = p >> 17;
    const float Minv = 1.0f / MCNT;
    float m = stats[o] * Minv;
    float v = stats[CO + o] * Minv - m * m;
    float scl = gamma[o] * rsqrtf(v + BNEPS);
    float sh  = beta[o] - m * scl;
    const size_t base = (size_t)b * CO * KS + (size_t)o * KS + s;
    float mx = -1e30f;
#pragma unroll
    for (int k = 0; k < KNB; ++k) {
        float val = __fmaf_rn(scl, y2[base + (size_t)k * NPT], sh) + idn[base + (size_t)k * NPT];
        val = fmaxf(val, 0.0f);
        mx = fmaxf(mx, val);
    }
    feat[p] = mx;
}

__global__ void zero_kernel(float* p, int n) {
    int i = blockIdx.x * blockDim.x + threadIdx.x;
    if (i < n) p[i] = 0.f;
}

extern "C" void kernel_launch(void* const* d_in, const int* in_sizes, int n_in,
                              void* d_out, int out_size, void* d_ws, size_t ws_size,
                              hipStream_t stream) {
    (void)in_sizes; (void)n_in; (void)out_size; (void)ws_size;
    const float* xyz    = (const float*)d_in[0];
    const float* points = (const float*)d_in[1];
    const float* proj_w = (const float*)d_in[2];
    const float* proj_g = (const float*)d_in[3];
    const float* proj_b = (const float*)d_in[4];
    const float* w1     = (const float*)d_in[5];   // (2,64,64)
    const float* g1     = (const float*)d_in[6];
    const float* b1     = (const float*)d_in[7];
    const float* w2     = (const float*)d_in[8];
    const float* g2     = (const float*)d_in[9];
    const float* b2     = (const float*)d_in[10];

    float* out0 = (float*)d_out;                   // (4,3,2048)
    float* feat = (float*)d_out + NB * 3 * NPT;    // (4,64,2048)

    // Workspace layout: small arrays first, then TWO big tensors (A, B).
    // Total: (1024 + 262144 + 2*16777216) * 4 B = 135.3 MB.
    float* stats = (float*)d_ws;                    // 5 x 128 (rounded to 1024)
    int*   idx   = (int*)((float*)d_ws + 1024);     // (4,2048,32)
    float* A     = (float*)(idx + NB * NPT * KNB);  // activation tensor
    float* B     = A + TELEM;                       // residual tensor

    // cloud copy (96 KB) + winner-coord staging (24 KB) + skey (64 B)
    const size_t fps_lds = (size_t)(3 * NPTS + 3 * NPT) * sizeof(float)
                         + 2 * FWAVES * sizeof(unsigned long long);  // 122,944 B

    hipLaunchKernelGGL(zero_kernel, dim3(3), dim3(256), 0, stream, stats, 5 * 2 * CO);
    hipLaunchKernelGGL(fps_kernel, dim3(NB), dim3(FTHR), fps_lds, stream, xyz, out0);
    hipLaunchKernelGGL(ballq_kernel, dim3(2048), dim3(256), 0, stream, xyz, out0, idx);
    // proj raw conv -> A, stats0
    hipLaunchKernelGGL(proj_kernel, dim3(1024), dim3(256), 0, stream,
                       xyz, points, out0, idx, proj_w, A, stats);
    // d=0: x = relu(bnP(A)); idn0 -> B; y1 -> A (in-place)
    hipLaunchKernelGGL((conv_bn_kernel<false, true>), dim3(1024), dim3(256), 0, stream,
                       A, (const float*)nullptr, stats, proj_g, proj_b, w1,
                       B, A, stats + 128);
    // d=0: y2 = conv(w2[0], relu(bn1(y1)))  A -> A
    hipLaunchKernelGGL((conv_bn_kernel<false, false>), dim3(1024), dim3(256), 0, stream,
                       A, (const float*)nullptr, stats + 128, g1, b1, w2,
                       (float*)nullptr, A, stats + 256);
    // d=1: x = relu(bn2(y2)+idn0); idn1 -> B (aliases idn read); y1 -> A
    hipLaunchKernelGGL((conv_bn_kernel<true, true>), dim3(1024), dim3(256), 0, stream,
                       A, B, stats + 256, g2, b2, w1 + CO * CO,
                       B, A, stats + 384);
    // d=1: y2 = conv(w2[1], relu(bn1'(y1)))  A -> A
    hipLaunchKernelGGL((conv_bn_kernel<false, false>), dim3(1024), dim3(256), 0, stream,
                       A, (const float*)nullptr, stats + 384, g1 + CO, b1 + CO, w2 + CO * CO,
                       (float*)nullptr, A, stats + 512);
    // feat = max_k relu(bn2'(A)+B)
    hipLaunchKernelGGL(final_kernel, dim3(2048), dim3(256), 0, stream,
                       A, B, stats + 512, g2 + CO, b2 + CO, feat);
}